// Round 1
// 148.546 us; speedup vs baseline: 1.0185x; 1.0185x over previous
//
#include <hip/hip_runtime.h>

// Z gate on qudits (DIM=2, S=1, INDEX={0,5,11}, L=24, N=2^24).
// omega = -1, so amplitude k is multiplied by (-1)^parity(bits {23,18,12} of k)
// [axis i -> bit (L-1-i)].
//
// Output layout: PLANAR float32 — real plane then imag plane (verified in a
// previous session; interleaved layout fails with the sqrt(2)-scramble
// signature).
//
// R3 change vs 151.2 µs baseline:
//  - NON-TEMPORAL stores for the output: output is write-once/never-re-read,
//    nt stores skip L2/L3 allocation so the 134 MB input set stays resident
//    in the 256 MB Infinity Cache across iterations -> read half becomes L3
//    hits instead of HBM fetches.
//  - Sign hoisted to a block-uniform scalar: lowest sign bit is bit 12
//    (4096-amplitude span); a 256-thread block covers 1024 aligned
//    amplitudes, so the sign is constant per block (SALU, frees the VALU
//    popc per lane — cosmetic, kernel is memory-bound).

#define SIGN_MASK ((1u << 23) | (1u << 18) | (1u << 12))

typedef float f32x4 __attribute__((ext_vector_type(4)));

__global__ void __launch_bounds__(256)
Z_50259707298066_kernel(const f32x4* __restrict__ xr,
                        const f32x4* __restrict__ xi,
                        f32x4* __restrict__ out,
                        unsigned n4,       // float4 count per plane
                        int has_imag) {
    unsigned j = blockIdx.x * blockDim.x + threadIdx.x;
    if (j >= n4) return;

    // First amplitude index covered by this block; sign bits are all >= 12,
    // so the sign is uniform across the block's 1024 amplitudes.
    unsigned block_base = (blockIdx.x * blockDim.x) << 2;
    float s = (__popc(block_base & SIGN_MASK) & 1) ? -1.0f : 1.0f;

    f32x4 r = xr[j];                       // cached load: keep inputs in L3
    __builtin_nontemporal_store(r * s, &out[j]);

    if (has_imag) {
        f32x4 im = xi[j];                  // cached load
        __builtin_nontemporal_store(im * s, &out[n4 + j]);
    }
}

extern "C" void kernel_launch(void* const* d_in, const int* in_sizes, int n_in,
                              void* d_out, int out_size, void* d_ws, size_t ws_size,
                              hipStream_t stream) {
    const f32x4* xr = (const f32x4*)d_in[0];
    const f32x4* xi = (const f32x4*)d_in[1];
    f32x4* out = (f32x4*)d_out;

    const unsigned n  = (unsigned)in_sizes[0];   // amplitudes (expect 2^24)
    const unsigned n4 = n >> 2;                  // float4 count per plane
    const int has_imag = (unsigned)out_size >= 2u * n;

    const unsigned block = 256;
    const unsigned grid  = (n4 + block - 1) / block;
    Z_50259707298066_kernel<<<grid, block, 0, stream>>>(xr, xi, out, n4, has_imag);
}